// Round 1
// baseline (668.612 us; speedup 1.0000x reference)
//
#include <hip/hip_runtime.h>
#include <hip/hip_bf16.h>
#include <stdint.h>

#define O_N 100000
#define T_N 400000

typedef __attribute__((ext_vector_type(8))) short short8;
typedef __attribute__((ext_vector_type(4))) float f32x4;

__device__ __forceinline__ unsigned short f2bf(float x) {
    union { float f; unsigned u; } v; v.f = x;
    unsigned u = v.u;
    unsigned rounded = u + 0x7FFF + ((u >> 16) & 1);
    return (unsigned short)(rounded >> 16);
}

// Pack a K x N column-slice of row-major W (leading dim ldw) into
// mfma_f32_16x16x32_bf16 B-fragment order:
// out[((kstep*Ntiles + ntile)*64 + lane)*8 + j] = bf16(W[kstep*32 + (lane>>4)*8 + j][col0 + ntile*16 + (lane&15)])
__global__ void pack_b(const float* __restrict__ W, unsigned short* __restrict__ out,
                       int K, int Ntiles, int ldw, int col0) {
    int idx = blockIdx.x * 256 + threadIdx.x;
    int total = K * Ntiles * 16;
    if (idx >= total) return;
    int j = idx & 7;
    int lane = (idx >> 3) & 63;
    int t2 = idx >> 9;
    int ntile = t2 % Ntiles;
    int kstep = t2 / Ntiles;
    int k = kstep * 32 + ((lane >> 4) << 3) + j;
    int n = (ntile << 4) + (lane & 15);
    out[idx] = f2bf(W[(size_t)k * ldw + col0 + n]);
}

__device__ __forceinline__ void stage_w(const unsigned short* __restrict__ src,
                                        unsigned short* __restrict__ dst, int tid) {
    const short8* s = reinterpret_cast<const short8*>(src);
    short8* d = reinterpret_cast<short8*>(dst);
    d[tid] = s[tid];
    d[tid + 256] = s[tid + 256];
}

// 64 triples per block, 4 waves; wave w computes rows 16w..16w+15.
__global__ __launch_bounds__(256, 2) void triples_kernel(
    const float* __restrict__ obj_vecs,
    const float* __restrict__ pred_vecs,
    const int* __restrict__ edges,
    const unsigned short* __restrict__ W1a_p, const float* __restrict__ b1a,
    const unsigned short* __restrict__ W1b_p, const float* __restrict__ b1b,
    float* __restrict__ pooled,
    float* __restrict__ new_p,
    float* __restrict__ counts)
{
    __shared__ __align__(16) unsigned short Apack[24576];   // 48 KB; first 8192 reused for h
    __shared__ __align__(16) unsigned short Wbuf[2][4096];  // 16 KB double buffer
    __shared__ int sseg[64], oseg[64];

    const int tid = threadIdx.x;
    const int lane = tid & 63;
    const int w = tid >> 6;
    const int t0 = blockIdx.x * 64;

    if (tid < 64) {
        int s = edges[2 * (t0 + tid)];
        int o = edges[2 * (t0 + tid) + 1];
        sseg[tid] = s;
        oseg[tid] = o;
        atomicAdd(&counts[s], 1.0f);
        atomicAdd(&counts[o], 1.0f);
    }
    __syncthreads();

    // Gather [obj[s] | pred | obj[o]] rows, fp32 -> bf16, into A-fragment-packed LDS.
    for (int it = 0; it < 24; ++it) {
        int idx = it * 256 + tid;
        int r = idx / 96;
        int c = (idx % 96) * 4;
        const float* srcp;
        if (c < 128)      srcp = obj_vecs  + (size_t)sseg[r] * 128 + c;
        else if (c < 256) srcp = pred_vecs + (size_t)(t0 + r) * 128 + (c - 128);
        else              srcp = obj_vecs  + (size_t)oseg[r] * 128 + (c - 256);
        f32x4 v = *reinterpret_cast<const f32x4*>(srcp);
        int off = (((r >> 4) * 12 + (c >> 5)) << 9)
                + (((r & 15) | (((c & 31) >> 3) << 4)) << 3) + (c & 7);
        Apack[off + 0] = f2bf(v[0]);
        Apack[off + 1] = f2bf(v[1]);
        Apack[off + 2] = f2bf(v[2]);
        Apack[off + 3] = f2bf(v[3]);
    }

    stage_w(W1a_p, Wbuf[0], tid);
    __syncthreads();

    // GEMM1: (64x384) @ (384x128) -> h
    f32x4 acc[8];
    #pragma unroll
    for (int n = 0; n < 8; ++n) acc[n] = (f32x4){0.f, 0.f, 0.f, 0.f};

    for (int kk = 0; kk < 12; ++kk) {
        if (kk < 11) stage_w(W1a_p + (kk + 1) * 4096, Wbuf[(kk + 1) & 1], tid);
        short8 a = *reinterpret_cast<const short8*>(&Apack[((w * 12 + kk) << 9) + (lane << 3)]);
        const unsigned short* wb = Wbuf[kk & 1];
        #pragma unroll
        for (int n = 0; n < 8; ++n) {
            short8 b = *reinterpret_cast<const short8*>(&wb[((n << 6) + lane) << 3]);
            acc[n] = __builtin_amdgcn_mfma_f32_16x16x32_bf16(a, b, acc[n], 0, 0, 0);
        }
        __syncthreads();
    }

    // h = relu(acc + b1a) -> bf16 A-fragment-packed into Apack[0..8191] (K=128)
    #pragma unroll
    for (int n = 0; n < 8; ++n) {
        int col = (n << 4) + (lane & 15);
        float bias = b1a[col];
        int base = ((w * 4 + (col >> 5)) << 9) + (col & 7);
        int chi = ((col & 31) >> 3) << 4;
        #pragma unroll
        for (int jj = 0; jj < 4; ++jj) {
            int rloc = ((lane >> 4) << 2) + jj;
            float hv = acc[n][jj] + bias;
            hv = hv > 0.f ? hv : 0.f;
            Apack[base + ((rloc | chi) << 3)] = f2bf(hv);
        }
    }

    // GEMM2 split into 3 column groups: g=0 -> new_s (atomic pooled), g=1 -> new_p, g=2 -> new_o (atomic pooled)
    for (int g = 0; g < 3; ++g) {
        const unsigned short* Wsrc = W1b_p + g * 16384;
        stage_w(Wsrc, Wbuf[0], tid);
        __syncthreads();

        f32x4 acc2[8];
        #pragma unroll
        for (int n = 0; n < 8; ++n) acc2[n] = (f32x4){0.f, 0.f, 0.f, 0.f};

        for (int kk = 0; kk < 4; ++kk) {
            if (kk < 3) stage_w(Wsrc + (kk + 1) * 4096, Wbuf[(kk + 1) & 1], tid);
            short8 a = *reinterpret_cast<const short8*>(&Apack[((w * 4 + kk) << 9) + (lane << 3)]);
            const unsigned short* wb = Wbuf[kk & 1];
            #pragma unroll
            for (int n = 0; n < 8; ++n) {
                short8 b = *reinterpret_cast<const short8*>(&wb[((n << 6) + lane) << 3]);
                acc2[n] = __builtin_amdgcn_mfma_f32_16x16x32_bf16(a, b, acc2[n], 0, 0, 0);
            }
            __syncthreads();
        }

        #pragma unroll
        for (int n = 0; n < 8; ++n) {
            int col = (n << 4) + (lane & 15);
            float bias = b1b[g * 128 + col];
            #pragma unroll
            for (int jj = 0; jj < 4; ++jj) {
                int rloc = (w << 4) + ((lane >> 4) << 2) + jj;
                float val = acc2[n][jj] + bias;
                if (g == 1) {
                    new_p[(size_t)(t0 + rloc) * 128 + col] = val;
                } else {
                    int seg = (g == 0) ? sseg[rloc] : oseg[rloc];
                    atomicAdd(&pooled[(size_t)seg * 128 + col], val);
                }
            }
        }
    }
}

// 64 object rows per block: normalize pooled by counts, 2-layer MLP, write new_obj in place.
__global__ __launch_bounds__(256, 2) void objects_kernel(
    const float* __restrict__ counts,
    const unsigned short* __restrict__ W2a_p, const float* __restrict__ b2a,
    const unsigned short* __restrict__ W2b_p, const float* __restrict__ b2b,
    float* __restrict__ inout)
{
    __shared__ __align__(16) unsigned short Apack[8192];
    __shared__ __align__(16) unsigned short Hpack[8192];
    __shared__ __align__(16) unsigned short Wbuf[2][4096];

    const int tid = threadIdx.x;
    const int lane = tid & 63;
    const int w = tid >> 6;
    const int r0 = blockIdx.x * 64;

    for (int it = 0; it < 8; ++it) {
        int idx = it * 256 + tid;
        int r = idx >> 5;
        int c = (idx & 31) << 2;
        int row = r0 + r;
        float vals[4] = {0.f, 0.f, 0.f, 0.f};
        if (row < O_N) {
            f32x4 v = *reinterpret_cast<const f32x4*>(&inout[(size_t)row * 128 + c]);
            float inv = 1.0f / fmaxf(counts[row], 1.0f);
            vals[0] = v[0] * inv; vals[1] = v[1] * inv;
            vals[2] = v[2] * inv; vals[3] = v[3] * inv;
        }
        int off = (((r >> 4) * 4 + (c >> 5)) << 9)
                + (((r & 15) | (((c & 31) >> 3) << 4)) << 3) + (c & 7);
        Apack[off + 0] = f2bf(vals[0]);
        Apack[off + 1] = f2bf(vals[1]);
        Apack[off + 2] = f2bf(vals[2]);
        Apack[off + 3] = f2bf(vals[3]);
    }

    stage_w(W2a_p, Wbuf[0], tid);
    __syncthreads();

    f32x4 acc[8];
    #pragma unroll
    for (int n = 0; n < 8; ++n) acc[n] = (f32x4){0.f, 0.f, 0.f, 0.f};

    for (int kk = 0; kk < 4; ++kk) {
        if (kk < 3) stage_w(W2a_p + (kk + 1) * 4096, Wbuf[(kk + 1) & 1], tid);
        short8 a = *reinterpret_cast<const short8*>(&Apack[((w * 4 + kk) << 9) + (lane << 3)]);
        const unsigned short* wb = Wbuf[kk & 1];
        #pragma unroll
        for (int n = 0; n < 8; ++n) {
            short8 b = *reinterpret_cast<const short8*>(&wb[((n << 6) + lane) << 3]);
            acc[n] = __builtin_amdgcn_mfma_f32_16x16x32_bf16(a, b, acc[n], 0, 0, 0);
        }
        __syncthreads();
    }

    #pragma unroll
    for (int n = 0; n < 8; ++n) {
        int col = (n << 4) + (lane & 15);
        float bias = b2a[col];
        int base = ((w * 4 + (col >> 5)) << 9) + (col & 7);
        int chi = ((col & 31) >> 3) << 4;
        #pragma unroll
        for (int jj = 0; jj < 4; ++jj) {
            int rloc = ((lane >> 4) << 2) + jj;
            float hv = acc[n][jj] + bias;
            hv = hv > 0.f ? hv : 0.f;
            Hpack[base + ((rloc | chi) << 3)] = f2bf(hv);
        }
    }

    stage_w(W2b_p, Wbuf[0], tid);
    __syncthreads();

    f32x4 acc2[8];
    #pragma unroll
    for (int n = 0; n < 8; ++n) acc2[n] = (f32x4){0.f, 0.f, 0.f, 0.f};

    for (int kk = 0; kk < 4; ++kk) {
        if (kk < 3) stage_w(W2b_p + (kk + 1) * 4096, Wbuf[(kk + 1) & 1], tid);
        short8 a = *reinterpret_cast<const short8*>(&Hpack[((w * 4 + kk) << 9) + (lane << 3)]);
        const unsigned short* wb = Wbuf[kk & 1];
        #pragma unroll
        for (int n = 0; n < 8; ++n) {
            short8 b = *reinterpret_cast<const short8*>(&wb[((n << 6) + lane) << 3]);
            acc2[n] = __builtin_amdgcn_mfma_f32_16x16x32_bf16(a, b, acc2[n], 0, 0, 0);
        }
        __syncthreads();
    }

    #pragma unroll
    for (int n = 0; n < 8; ++n) {
        int col = (n << 4) + (lane & 15);
        float bias = b2b[col];
        #pragma unroll
        for (int jj = 0; jj < 4; ++jj) {
            int rloc = (w << 4) + ((lane >> 4) << 2) + jj;
            int row = r0 + rloc;
            if (row < O_N) inout[(size_t)row * 128 + col] = acc2[n][jj] + bias;
        }
    }
}

extern "C" void kernel_launch(void* const* d_in, const int* in_sizes, int n_in,
                              void* d_out, int out_size, void* d_ws, size_t ws_size,
                              hipStream_t stream)
{
    const float* obj   = (const float*)d_in[0];
    const float* pred  = (const float*)d_in[1];
    const int*   edges = (const int*)d_in[2];
    const float* W1a = (const float*)d_in[3];
    const float* b1a = (const float*)d_in[4];
    const float* W1b = (const float*)d_in[5];
    const float* b1b = (const float*)d_in[6];
    const float* W2a = (const float*)d_in[7];
    const float* b2a = (const float*)d_in[8];
    const float* W2b = (const float*)d_in[9];
    const float* b2b = (const float*)d_in[10];

    float* out    = (float*)d_out;
    float* pooled = out;                       // O x 128 accumulated in place, then overwritten by new_obj
    float* new_p  = out + (size_t)O_N * 128;   // T x 128

    uintptr_t wsbase = (uintptr_t)d_ws;
    float* counts = (float*)wsbase;
    uintptr_t p = (wsbase + (size_t)O_N * 4 + 255) & ~(uintptr_t)255;
    unsigned short* W1a_p = (unsigned short*)p;  p += (size_t)49152 * 2;
    unsigned short* W1b_p = (unsigned short*)p;  p += (size_t)49152 * 2;
    unsigned short* W2a_p = (unsigned short*)p;  p += (size_t)16384 * 2;
    unsigned short* W2b_p = (unsigned short*)p;

    hipMemsetAsync(pooled, 0, (size_t)O_N * 128 * sizeof(float), stream);
    hipMemsetAsync(counts, 0, (size_t)O_N * sizeof(float), stream);

    pack_b<<<192, 256, 0, stream>>>(W1a, W1a_p, 384, 8, 128, 0);
    pack_b<<<64, 256, 0, stream>>>(W1b, W1b_p,         128, 8, 384, 0);
    pack_b<<<64, 256, 0, stream>>>(W1b, W1b_p + 16384, 128, 8, 384, 128);
    pack_b<<<64, 256, 0, stream>>>(W1b, W1b_p + 32768, 128, 8, 384, 256);
    pack_b<<<64, 256, 0, stream>>>(W2a, W2a_p, 128, 8, 128, 0);
    pack_b<<<64, 256, 0, stream>>>(W2b, W2b_p, 128, 8, 128, 0);

    triples_kernel<<<T_N / 64, 256, 0, stream>>>(obj, pred, edges,
                                                 W1a_p, b1a, W1b_p, b1b,
                                                 pooled, new_p, counts);
    objects_kernel<<<(O_N + 63) / 64, 256, 0, stream>>>(counts, W2a_p, b2a, W2b_p, b2b, out);
}